// Round 1
// 277.694 us; speedup vs baseline: 1.0338x; 1.0338x over previous
//
#include <hip/hip_runtime.h>

// DynamicFC: out[b,o,h,w] = sum_i w[b,o,i] * x[b,i,h,w] + bias[b,o]
// Batched GEMM per b: M=Cout=512, N=HW=784, K=Cin=512, fp32 in/out.
// fp32 -> bf16 convert during LDS staging, mfma_f32_16x16x32_bf16, fp32 acc.
// R3 changes vs R2:
//  - BN 128 -> 112 (784 = 7*112 exactly): kills the 87.5%-masked tail tile
//    (-12.5% total MFMA work), removes store guard + load clamp.
//    Waves now 4x(32 rows x 112 cols) = 2x7 frags, 14 MFMA/K-step/wave.
//  - Software pipeline: next K-tile's global loads are issued into REGISTERS
//    right after the first barrier, so their ~200-400cy L2/L3 latency hides
//    under ds_read + MFMA of the current tile instead of sitting on the
//    critical path (kernel was latency-bound: MfmaUtil 8%, HBM 19%, occ 27%).

#define CIN  512
#define COUT 512
#define HW   784      // 28*28 = 7*112
#define BM   128
#define BN   112
#define BK   32
#define LDS_STRIDE 40 // 32 + 8 pad (keeps 16B alignment, balances banks)

typedef __bf16 bf16_t;
typedef __bf16 bf16x8 __attribute__((ext_vector_type(8)));
typedef __bf16 bf16x4 __attribute__((ext_vector_type(4)));
typedef float  f32x4  __attribute__((ext_vector_type(4)));

__device__ __forceinline__ bf16x8 pack8(f32x4 a, f32x4 b) {
    bf16x8 r;
    r[0] = (bf16_t)a[0]; r[1] = (bf16_t)a[1];
    r[2] = (bf16_t)a[2]; r[3] = (bf16_t)a[3];
    r[4] = (bf16_t)b[0]; r[5] = (bf16_t)b[1];
    r[6] = (bf16_t)b[2]; r[7] = (bf16_t)b[3];
    return r;
}

__global__ __launch_bounds__(256) void dynfc_kernel(
    const float* __restrict__ x,     // [64][512][784]
    const float* __restrict__ w,     // [64][512][512]
    const float* __restrict__ bias,  // [64][512]
    float* __restrict__ out)         // [64][512][784]
{
    __shared__ bf16_t Asm[BM * LDS_STRIDE];   // [m][k], k-contiguous
    __shared__ bf16_t Bsm[BN * LDS_STRIDE];   // [n][k], k-contiguous (B^T form)
    __shared__ float  bias_sm[BM];

    // XCD swizzle: give each XCD whole batches so W (1MB) + X (1.6MB)
    // re-reads hit that XCD's private L2.
    const int bid   = blockIdx.x;        // 0..1791
    const int xcd   = bid & 7;
    const int j     = bid >> 3;          // 0..223
    const int batch = xcd + 8 * (j / 28);
    const int trem  = j % 28;            // 4 m-tiles * 7 n-tiles
    const int tm    = trem / 7;
    const int tn    = trem % 7;
    const int m0    = tm * BM;
    const int n0    = tn * BN;           // 0,112,...,672 — exact cover of 784

    const int tid  = threadIdx.x;
    const int lane = tid & 63;
    const int wid  = tid >> 6;
    const int wm   = wid * 32;           // wave's 32-row slice of the 128-row tile
    const int l15  = lane & 15;
    const int quad = lane >> 4;

    const float* xb = x + (size_t)batch * CIN * HW;
    const float* wb = w + (size_t)batch * COUT * CIN;

    if (tid < 32) {
        f32x4 bv = *(const f32x4*)(bias + batch * COUT + m0 + tid * 4);
        *(f32x4*)&bias_sm[tid * 4] = bv;
    }

    // A staging: thread -> (row ar of 128, k-half ah of {0,16}); 16 fp32 each
    const int ar = tid >> 1;
    const int ah = (tid & 1) * 16;
    // B staging: thread -> 4x4 micro-tile; kg = k-group (0..7), ng = n-group.
    // 32k x 112n = 224 micro-tiles -> threads 224..255 idle for B.
    const int  kg      = tid & 7;
    const int  ng      = tid >> 3;       // 0..31
    const bool bactive = (ng < 28);

    const float* asrc = wb + (size_t)(m0 + ar) * CIN + ah;
    const float* bsrc = xb + (size_t)(kg * 4) * HW + n0 + ng * 4;

    // ---- prologue: load K-tile 0 into registers ----
    f32x4 a0, a1, a2, a3, r0, r1, r2, r3;
    a0 = *(const f32x4*)(asrc);
    a1 = *(const f32x4*)(asrc + 4);
    a2 = *(const f32x4*)(asrc + 8);
    a3 = *(const f32x4*)(asrc + 12);
    if (bactive) {
        r0 = *(const f32x4*)(bsrc);
        r1 = *(const f32x4*)(bsrc + HW);
        r2 = *(const f32x4*)(bsrc + 2 * HW);
        r3 = *(const f32x4*)(bsrc + 3 * HW);
    }

    f32x4 acc[2][7] = {};

    for (int k0 = 0; k0 < CIN; k0 += BK) {
        // ---- write current tile (already in regs) to LDS, converting ----
        *(bf16x8*)&Asm[ar * LDS_STRIDE + ah]     = pack8(a0, a1);
        *(bf16x8*)&Asm[ar * LDS_STRIDE + ah + 8] = pack8(a2, a3);
        if (bactive) {
            #pragma unroll
            for (int nn = 0; nn < 4; nn++) {
                bf16x4 col;
                col[0] = (bf16_t)r0[nn];
                col[1] = (bf16_t)r1[nn];
                col[2] = (bf16_t)r2[nn];
                col[3] = (bf16_t)r3[nn];
                *(bf16x4*)&Bsm[(ng * 4 + nn) * LDS_STRIDE + kg * 4] = col;
            }
        }
        __syncthreads();

        // ---- prefetch NEXT K-tile into registers; latency hides under MFMA ----
        if (k0 + BK < CIN) {
            const float* ap = asrc + k0 + BK;
            a0 = *(const f32x4*)(ap);
            a1 = *(const f32x4*)(ap + 4);
            a2 = *(const f32x4*)(ap + 8);
            a3 = *(const f32x4*)(ap + 12);
            if (bactive) {
                const float* bp = bsrc + (size_t)(k0 + BK) * HW;
                r0 = *(const f32x4*)(bp);
                r1 = *(const f32x4*)(bp + HW);
                r2 = *(const f32x4*)(bp + 2 * HW);
                r3 = *(const f32x4*)(bp + 3 * HW);
            }
        }

        // ---- fragments + MFMA (2 m-frags x 7 n-frags) ----
        bf16x8 af[2], bfr[7];
        #pragma unroll
        for (int i = 0; i < 2; i++)
            af[i] = *(const bf16x8*)&Asm[(wm + i * 16 + l15) * LDS_STRIDE + quad * 8];
        #pragma unroll
        for (int j2 = 0; j2 < 7; j2++)
            bfr[j2] = *(const bf16x8*)&Bsm[(j2 * 16 + l15) * LDS_STRIDE + quad * 8];
        #pragma unroll
        for (int i = 0; i < 2; i++)
            #pragma unroll
            for (int j2 = 0; j2 < 7; j2++)
                acc[i][j2] = __builtin_amdgcn_mfma_f32_16x16x32_bf16(af[i], bfr[j2], acc[i][j2], 0, 0, 0);
        __syncthreads();
    }

    // ---- epilogue: add bias, nontemporal store (no guard: 7*112 == 784) ----
    // C/D layout: col = lane&15, row = quad*4 + r
    float* ob = out + (size_t)batch * COUT * HW;
    #pragma unroll
    for (int j2 = 0; j2 < 7; j2++) {
        const int n = n0 + j2 * 16 + l15;
        #pragma unroll
        for (int i = 0; i < 2; i++) {
            #pragma unroll
            for (int r = 0; r < 4; r++) {
                const int m = wm + i * 16 + quad * 4 + r;
                __builtin_nontemporal_store(acc[i][j2][r] + bias_sm[m],
                                            &ob[(size_t)(m0 + m) * HW + n]);
            }
        }
    }
}

extern "C" void kernel_launch(void* const* d_in, const int* in_sizes, int n_in,
                              void* d_out, int out_size, void* d_ws, size_t ws_size,
                              hipStream_t stream) {
    (void)in_sizes; (void)n_in; (void)d_ws; (void)ws_size; (void)out_size;
    const float* x    = (const float*)d_in[0];
    const float* w    = (const float*)d_in[1];
    const float* bias = (const float*)d_in[2];
    float* out        = (float*)d_out;

    dim3 grid(64 * 4 * 7);   // 64 batches * 4 m-tiles * 7 n-tiles
    dim3 block(256);
    dynfc_kernel<<<grid, block, 0, stream>>>(x, w, bias, out);
}